// Round 1
// baseline (253.416 us; speedup 1.0000x reference)
//
#include <hip/hip_runtime.h>
#include <stdint.h>

// fused MLP: out = where(ti==0, 0.3*28700, sigmoid(MLP(emb[ti-1], fourier(rho)) + logit(0.3)) * 28700)
// MFMA f16 path, wave = 16 points, weights resident in registers.

typedef _Float16 half8 __attribute__((ext_vector_type(8)));
typedef float f32x4 __attribute__((ext_vector_type(4)));

#define LOG2E 1.44269504088896340736f
#define BASE_LOGIT -0.84729786038720367f   // log(0.3/0.7)
#define CSANMAX 28700.0f
#define IC_VAL 8610.0f                     // 0.3 * 28700

__device__ __forceinline__ float fast_exp2(float x) {
#if __has_builtin(__builtin_amdgcn_exp2f)
  return __builtin_amdgcn_exp2f(x);
#else
  return exp2f(x);
#endif
}
__device__ __forceinline__ float fast_rcp(float x) {
#if __has_builtin(__builtin_amdgcn_rcpf)
  return __builtin_amdgcn_rcpf(x);
#else
  return 1.0f / x;
#endif
}
__device__ __forceinline__ float sigf(float x) {
  return fast_rcp(1.0f + fast_exp2(-LOG2E * x));
}

__global__ __launch_bounds__(256) void mlp_kernel(
    const int* __restrict__ tix, const float* __restrict__ rho,
    const float* __restrict__ emb, const float* __restrict__ W0,
    const float* __restrict__ b0, const float* __restrict__ W1,
    const float* __restrict__ b1, const float* __restrict__ Wout,
    const float* __restrict__ bout, float* __restrict__ out, int nt4)
{
  // wave-private LDS regions. Feature region stride 40 halfs (80B, 16B-aligned,
  // 2-way banks = free). h region stride 72 halfs (144B, 16B-aligned, 2-way reads).
  __shared__ __align__(16) _Float16 ldsF[4][16][40];
  __shared__ __align__(16) _Float16 ldsH[4][16][72];

  const int tid  = threadIdx.x;
  const int wave = tid >> 6;
  const int lane = tid & 63;
  const int m    = lane & 15;   // point-in-tile (A rows / C cols) or N index (B)
  const int q    = lane >> 4;   // quad: k-group for A/B, row-group for C

  _Float16 (*F)[40] = ldsF[wave];
  _Float16 (*H)[72] = ldsH[wave];

  // ---- one-time: weight fragments (B-layout: B[k=q*8+j][n=m]) ----
  half8 B0f[4][2], B1f[4][2], B2f[2];
#pragma unroll
  for (int t = 0; t < 4; ++t) {
#pragma unroll
    for (int s = 0; s < 2; ++s) {
      half8 f0, f1;
#pragma unroll
      for (int j = 0; j < 8; ++j) {
        const int k = s * 32 + q * 8 + j;
        const int n = t * 16 + m;
        // pad K 49->64; fold b0 into k==49 slot (input feature there is 1.0)
        const float v0 = (k < 49) ? W0[k * 64 + n] : ((k == 49) ? b0[n] : 0.0f);
        f0[j] = (_Float16)v0;
        f1[j] = (_Float16)W1[k * 64 + n];
      }
      B0f[t][s] = f0;
      B1f[t][s] = f1;
    }
  }
#pragma unroll
  for (int s = 0; s < 2; ++s) {
    half8 f;
#pragma unroll
    for (int j = 0; j < 8; ++j) {
      const int k = s * 32 + q * 8 + j;
      f[j] = (m == 0) ? (_Float16)Wout[k] : (_Float16)0.0f;
    }
    B2f[s] = f;
  }
  float b1n[4];
#pragma unroll
  for (int t = 0; t < 4; ++t) b1n[t] = b1[t * 16 + m];
  const float boutBL = bout[0] + BASE_LOGIT;

  // one-time: constant feature columns. region col i = input k = 32+i.
  // i==17 -> k=49 -> 1.0 (bias slot); i in 18..31 -> 0 (K padding).
  if (lane < 16) {
#pragma unroll
    for (int i = 17; i < 32; ++i)
      F[lane][i] = (_Float16)((i == 17) ? 1.0f : 0.0f);
  }

  const f32x4 z = {0.0f, 0.0f, 0.0f, 0.0f};

  for (int g = blockIdx.x; g < nt4; g += gridDim.x) {
    const int tile = g * 4 + wave;   // nt4 = npoints/64, always 4 full tiles/block
    const int base = tile * 16;

    // ---- P1: per-point loads + Fourier features (Chebyshev: 1 cos + 1 sin) ----
    int ti = 0;
    if (lane < 16) {
      ti = tix[base + lane];
      const float rh = rho[base + lane];
      F[lane][0] = (_Float16)rh;
      const float rev = 0.5f * rh;  // v_sin/v_cos take revolutions: k*pi*rho rad = k*rho/2 rev
      const float c1 = __builtin_amdgcn_cosf(rev);
      const float s1 = __builtin_amdgcn_sinf(rev);
      F[lane][1] = (_Float16)c1;
      F[lane][9] = (_Float16)s1;
      float cm2 = 1.0f, cm1 = c1, sm2 = 0.0f, sm1 = s1;
      const float tc = 2.0f * c1;
#pragma unroll
      for (int k = 2; k <= 8; ++k) {
        const float ck = tc * cm1 - cm2;
        const float sk = tc * sm1 - sm2;
        F[lane][k] = (_Float16)ck;
        F[lane][8 + k] = (_Float16)sk;
        cm2 = cm1; cm1 = ck; sm2 = sm1; sm1 = sk;
      }
    }
    // emb gather straight into A-fragment kstep0: lane holds A[m][q*8+j]
    const int tim = __shfl(ti, m, 64);
    const int idxm = min(max(tim - 1, 0), 510);
    const float* erow = emb + (size_t)idxm * 32 + q * 8;
    const f32x4 e0 = *(const f32x4*)erow;
    const f32x4 e1 = *(const f32x4*)(erow + 4);
    half8 A0s0;
#pragma unroll
    for (int j = 0; j < 4; ++j) {
      A0s0[j]     = (_Float16)e0[j];
      A0s0[4 + j] = (_Float16)e1[j];
    }

    __syncthreads();  // features visible

    // ---- P2: layer 0 ----
    const half8 A0s1 = *(const half8*)&F[m][q * 8];
    f32x4 acc[4];
#pragma unroll
    for (int t = 0; t < 4; ++t) {
      f32x4 a = __builtin_amdgcn_mfma_f32_16x16x32_f16(A0s0, B0f[t][0], z, 0, 0, 0);
      a = __builtin_amdgcn_mfma_f32_16x16x32_f16(A0s1, B0f[t][1], a, 0, 0, 0);
      acc[t] = a;
    }
    // silu (b0 already folded) and transpose via LDS: C layout row=q*4+r, col=t*16+m
#pragma unroll
    for (int t = 0; t < 4; ++t)
#pragma unroll
      for (int r = 0; r < 4; ++r) {
        const float v = acc[t][r];
        H[q * 4 + r][t * 16 + m] = (_Float16)(v * sigf(v));
      }

    __syncthreads();  // h1 visible

    // ---- P3: layer 1 ----
    const half8 A1s0 = *(const half8*)&H[m][q * 8];
    const half8 A1s1 = *(const half8*)&H[m][32 + q * 8];

    __syncthreads();  // all reads done before overwrite

#pragma unroll
    for (int t = 0; t < 4; ++t) {
      f32x4 a = __builtin_amdgcn_mfma_f32_16x16x32_f16(A1s0, B1f[t][0], z, 0, 0, 0);
      a = __builtin_amdgcn_mfma_f32_16x16x32_f16(A1s1, B1f[t][1], a, 0, 0, 0);
      acc[t] = a;
    }
#pragma unroll
    for (int t = 0; t < 4; ++t)
#pragma unroll
      for (int r = 0; r < 4; ++r) {
        const float v = acc[t][r] + b1n[t];
        H[q * 4 + r][t * 16 + m] = (_Float16)(v * sigf(v));
      }

    __syncthreads();  // h2 visible

    // ---- P4: output layer (Wout in B col 0) + epilogue ----
    const half8 A2s0 = *(const half8*)&H[m][q * 8];
    const half8 A2s1 = *(const half8*)&H[m][32 + q * 8];
    f32x4 a2 = __builtin_amdgcn_mfma_f32_16x16x32_f16(A2s0, B2f[0], z, 0, 0, 0);
    a2 = __builtin_amdgcn_mfma_f32_16x16x32_f16(A2s1, B2f[1], a2, 0, 0, 0);

    f32x4 o;
#pragma unroll
    for (int r = 0; r < 4; ++r) {
      const int tir = __shfl(ti, q * 4 + r, 64);
      const float theta = sigf(a2[r] + boutBL);
      o[r] = (tir == 0) ? IC_VAL : theta * CSANMAX;
    }
    if (m == 0) *(f32x4*)(out + base + q * 4) = o;  // lanes 0,16,32,48 -> 16 floats
  }
}

extern "C" void kernel_launch(void* const* d_in, const int* in_sizes, int n_in,
                              void* d_out, int out_size, void* d_ws, size_t ws_size,
                              hipStream_t stream) {
  const int*   tix  = (const int*)d_in[0];
  const float* rho  = (const float*)d_in[1];
  const float* emb  = (const float*)d_in[2];
  const float* W0   = (const float*)d_in[3];
  const float* b0   = (const float*)d_in[4];
  const float* W1   = (const float*)d_in[5];
  const float* b1   = (const float*)d_in[6];
  const float* Wout = (const float*)d_in[7];
  const float* bout = (const float*)d_in[8];
  float* outp = (float*)d_out;

  const int n   = in_sizes[0];      // 2,000,000 (divisible by 64)
  const int nt4 = n / 64;           // 4 tiles of 16 points per block-group

  int grid = 768;                   // 3 blocks/CU target, grid-stride over nt4
  if (grid > nt4) grid = nt4;
  mlp_kernel<<<dim3(grid), dim3(256), 0, stream>>>(
      tix, rho, emb, W0, b0, W1, b1, Wout, bout, outp, nt4);
}

// Round 2
// 232.758 us; speedup vs baseline: 1.0888x; 1.0888x over previous
//
#include <hip/hip_runtime.h>
#include <stdint.h>

// fused MLP: out = where(ti==0, 0.3*28700, sigmoid(MLP(emb[ti-1], fourier(rho)) + logit(0.3)) * 28700)
// MFMA f16 path. Block = ONE wave (64 threads) so __syncthreads() lowers to a
// wave-level s_waitcnt (LDS is wave-private; no inter-wave coupling).

typedef _Float16 half8 __attribute__((ext_vector_type(8)));
typedef float f32x4 __attribute__((ext_vector_type(4)));

#define LOG2E 1.44269504088896340736f
#define BASE_LOGIT -0.84729786038720367f   // log(0.3/0.7)
#define CSANMAX 28700.0f
#define IC_VAL 8610.0f                     // 0.3 * 28700

__device__ __forceinline__ float fast_exp2(float x) {
#if __has_builtin(__builtin_amdgcn_exp2f)
  return __builtin_amdgcn_exp2f(x);
#else
  return exp2f(x);
#endif
}
__device__ __forceinline__ float fast_rcp(float x) {
#if __has_builtin(__builtin_amdgcn_rcpf)
  return __builtin_amdgcn_rcpf(x);
#else
  return 1.0f / x;
#endif
}
__device__ __forceinline__ float sigf(float x) {
  return fast_rcp(1.0f + fast_exp2(-LOG2E * x));
}

__global__ __launch_bounds__(64) void mlp_kernel(
    const int* __restrict__ tix, const float* __restrict__ rho,
    const float* __restrict__ emb, const float* __restrict__ W0,
    const float* __restrict__ b0, const float* __restrict__ W1,
    const float* __restrict__ b1, const float* __restrict__ Wout,
    const float* __restrict__ bout, float* __restrict__ out, int ntiles)
{
  // single-wave block: LDS regions are block == wave private.
  // F stride 40 halfs (80B, 16B-aligned). H stride 72 halfs (144B, 16B-aligned).
  __shared__ __align__(16) _Float16 F[16][40];
  __shared__ __align__(16) _Float16 H[16][72];

  const int lane = threadIdx.x;  // 0..63
  const int m    = lane & 15;    // point-in-tile (A rows / C cols) or N index (B)
  const int q    = lane >> 4;    // quad: k-group for A/B, row-group for C

  // ---- one-time: weight fragments (B-layout: B[k=q*8+j][n=m]) ----
  half8 B0f[4][2], B1f[4][2], B2f[2];
#pragma unroll
  for (int t = 0; t < 4; ++t) {
#pragma unroll
    for (int s = 0; s < 2; ++s) {
      half8 f0, f1;
#pragma unroll
      for (int j = 0; j < 8; ++j) {
        const int k = s * 32 + q * 8 + j;
        const int n = t * 16 + m;
        // pad K 49->64; fold b0 into k==49 slot (input feature there is 1.0)
        const float v0 = (k < 49) ? W0[k * 64 + n] : ((k == 49) ? b0[n] : 0.0f);
        f0[j] = (_Float16)v0;
        f1[j] = (_Float16)W1[k * 64 + n];
      }
      B0f[t][s] = f0;
      B1f[t][s] = f1;
    }
  }
#pragma unroll
  for (int s = 0; s < 2; ++s) {
    half8 f;
#pragma unroll
    for (int j = 0; j < 8; ++j) {
      const int k = s * 32 + q * 8 + j;
      f[j] = (m == 0) ? (_Float16)Wout[k] : (_Float16)0.0f;
    }
    B2f[s] = f;
  }
  float b1n[4];
#pragma unroll
  for (int t = 0; t < 4; ++t) b1n[t] = b1[t * 16 + m];
  const float boutBL = bout[0] + BASE_LOGIT;

  // one-time: constant feature columns. region col i = input k = 32+i.
  // i==17 -> k=49 -> 1.0 (bias slot); i in 18..31 -> 0 (K padding).
  if (lane < 16) {
#pragma unroll
    for (int i = 17; i < 32; ++i)
      F[lane][i] = (_Float16)((i == 17) ? 1.0f : 0.0f);
  }

  const f32x4 z = {0.0f, 0.0f, 0.0f, 0.0f};

  for (int tile = blockIdx.x; tile < ntiles; tile += gridDim.x) {
    const int base = tile * 16;

    // ---- P1: per-point loads + Fourier features (Chebyshev: 1 cos + 1 sin) ----
    int ti = 0;
    if (lane < 16) {
      ti = tix[base + lane];
      const float rh = rho[base + lane];
      F[lane][0] = (_Float16)rh;
      const float rev = 0.5f * rh;  // v_sin/v_cos take revolutions: k*pi*rho rad = k*rho/2 rev
      const float c1 = __builtin_amdgcn_cosf(rev);
      const float s1 = __builtin_amdgcn_sinf(rev);
      F[lane][1] = (_Float16)c1;
      F[lane][9] = (_Float16)s1;
      float cm2 = 1.0f, cm1 = c1, sm2 = 0.0f, sm1 = s1;
      const float tc = 2.0f * c1;
#pragma unroll
      for (int k = 2; k <= 8; ++k) {
        const float ck = tc * cm1 - cm2;
        const float sk = tc * sm1 - sm2;
        F[lane][k] = (_Float16)ck;
        F[lane][8 + k] = (_Float16)sk;
        cm2 = cm1; cm1 = ck; sm2 = sm1; sm1 = sk;
      }
    }
    // emb gather straight into A-fragment kstep0: lane holds A[m][q*8+j]
    const int tim = __shfl(ti, m, 64);
    const int idxm = min(max(tim - 1, 0), 510);
    const float* erow = emb + (size_t)idxm * 32 + q * 8;
    const f32x4 e0 = *(const f32x4*)erow;
    const f32x4 e1 = *(const f32x4*)(erow + 4);
    half8 A0s0;
#pragma unroll
    for (int j = 0; j < 4; ++j) {
      A0s0[j]     = (_Float16)e0[j];
      A0s0[4 + j] = (_Float16)e1[j];
    }

    __syncthreads();  // single-wave: lowers to s_waitcnt lgkmcnt(0)

    // ---- P2: layer 0 ----
    const half8 A0s1 = *(const half8*)&F[m][q * 8];
    f32x4 acc[4];
#pragma unroll
    for (int t = 0; t < 4; ++t) {
      f32x4 a = __builtin_amdgcn_mfma_f32_16x16x32_f16(A0s0, B0f[t][0], z, 0, 0, 0);
      a = __builtin_amdgcn_mfma_f32_16x16x32_f16(A0s1, B0f[t][1], a, 0, 0, 0);
      acc[t] = a;
    }
    // silu (b0 already folded) and transpose via LDS: C layout row=q*4+r, col=t*16+m
#pragma unroll
    for (int t = 0; t < 4; ++t)
#pragma unroll
      for (int r = 0; r < 4; ++r) {
        const float v = acc[t][r];
        H[q * 4 + r][t * 16 + m] = (_Float16)(v * sigf(v));
      }

    __syncthreads();  // h1 visible

    // ---- P3: layer 1 ----
    const half8 A1s0 = *(const half8*)&H[m][q * 8];
    const half8 A1s1 = *(const half8*)&H[m][32 + q * 8];

    __syncthreads();  // reads drained before overwrite

#pragma unroll
    for (int t = 0; t < 4; ++t) {
      f32x4 a = __builtin_amdgcn_mfma_f32_16x16x32_f16(A1s0, B1f[t][0], z, 0, 0, 0);
      a = __builtin_amdgcn_mfma_f32_16x16x32_f16(A1s1, B1f[t][1], a, 0, 0, 0);
      acc[t] = a;
    }
#pragma unroll
    for (int t = 0; t < 4; ++t)
#pragma unroll
      for (int r = 0; r < 4; ++r) {
        const float v = acc[t][r] + b1n[t];
        H[q * 4 + r][t * 16 + m] = (_Float16)(v * sigf(v));
      }

    __syncthreads();  // h2 visible

    // ---- P4: output layer (Wout in B col 0) + epilogue ----
    const half8 A2s0 = *(const half8*)&H[m][q * 8];
    const half8 A2s1 = *(const half8*)&H[m][32 + q * 8];
    f32x4 a2 = __builtin_amdgcn_mfma_f32_16x16x32_f16(A2s0, B2f[0], z, 0, 0, 0);
    a2 = __builtin_amdgcn_mfma_f32_16x16x32_f16(A2s1, B2f[1], a2, 0, 0, 0);

    f32x4 o;
#pragma unroll
    for (int r = 0; r < 4; ++r) {
      const int tir = __shfl(ti, q * 4 + r, 64);
      const float theta = sigf(a2[r] + boutBL);
      o[r] = (tir == 0) ? IC_VAL : theta * CSANMAX;
    }
    if (m == 0) *(f32x4*)(out + base + q * 4) = o;  // lanes 0,16,32,48 -> 16 floats
  }
}

extern "C" void kernel_launch(void* const* d_in, const int* in_sizes, int n_in,
                              void* d_out, int out_size, void* d_ws, size_t ws_size,
                              hipStream_t stream) {
  const int*   tix  = (const int*)d_in[0];
  const float* rho  = (const float*)d_in[1];
  const float* emb  = (const float*)d_in[2];
  const float* W0   = (const float*)d_in[3];
  const float* b0   = (const float*)d_in[4];
  const float* W1   = (const float*)d_in[5];
  const float* b1   = (const float*)d_in[6];
  const float* Wout = (const float*)d_in[7];
  const float* bout = (const float*)d_in[8];
  float* outp = (float*)d_out;

  const int n      = in_sizes[0];   // 2,000,000 (divisible by 16)
  const int ntiles = n / 16;        // 125,000 tiles of 16 points

  // 1 wave per block; 16 blocks/CU (VGPR limit 4 waves/SIMD) -> grid 4096
  int grid = 4096;
  if (grid > ntiles) grid = ntiles;
  mlp_kernel<<<dim3(grid), dim3(64), 0, stream>>>(
      tix, rho, emb, W0, b0, W1, b1, Wout, bout, outp, ntiles);
}

// Round 3
// 199.718 us; speedup vs baseline: 1.2689x; 1.1654x over previous
//
#include <hip/hip_runtime.h>
#include <stdint.h>

// Fused MLP decode, MFMA f16. Wave = 64 points (4 sub-tiles of 16).
// L0 computed transposed (W^T·X^T) -> contiguous packed-f16 LDS stores;
// L1 untransposed; final 64->1 layer as in-register dot + butterfly reduce.

typedef _Float16 half8 __attribute__((ext_vector_type(8)));
typedef _Float16 half4v __attribute__((ext_vector_type(4)));
typedef float f32x4 __attribute__((ext_vector_type(4)));

#define LOG2E 1.44269504088896340736f
#define BASE_LOGIT -0.84729786038720367f   // log(0.3/0.7)
#define CSANMAX 28700.0f
#define IC_VAL 8610.0f                     // 0.3 * 28700

__device__ __forceinline__ float fast_exp2(float x) { return __builtin_amdgcn_exp2f(x); }
__device__ __forceinline__ float fast_rcp(float x)  { return __builtin_amdgcn_rcpf(x); }
__device__ __forceinline__ float sigf(float x)  { return fast_rcp(1.0f + fast_exp2(-LOG2E * x)); }
__device__ __forceinline__ float siluf(float x) { return x * sigf(x); }

__global__ __launch_bounds__(64, 4) void mlp_kernel(
    const int* __restrict__ tix, const float* __restrict__ rho,
    const float* __restrict__ emb, const float* __restrict__ W0,
    const float* __restrict__ b0, const float* __restrict__ W1,
    const float* __restrict__ b1, const float* __restrict__ Wout,
    const float* __restrict__ bout, float* __restrict__ out, int ngroups)
{
  // F: features for 64 points, stride 40 halfs (80B: 16B-aligned, m/m+8 2-way banks = free)
  // H: one 16-pt sub-tile's h1, double-buffered, stride 72 halfs (144B)
  __shared__ __align__(16) _Float16 F[64][40];
  __shared__ __align__(16) _Float16 H[2][16][72];

  const int lane = threadIdx.x;  // 0..63
  const int m    = lane & 15;
  const int q    = lane >> 4;

  // ---- one-time: weight fragments ----
  // B-layout content B[k=s*32+q*8+j][n=t*16+m]; used as A-op for L0 (=> W^T), B-op for L1.
  half8 B0f[4][2], B1f[4][2];
#pragma unroll
  for (int t = 0; t < 4; ++t) {
#pragma unroll
    for (int s = 0; s < 2; ++s) {
      half8 f0, f1;
#pragma unroll
      for (int j = 0; j < 8; ++j) {
        const int k = s * 32 + q * 8 + j;
        const int n = t * 16 + m;
        // pad K 49->64; fold b0 into k==49 (feature there is 1.0)
        const float v0 = (k < 49) ? W0[k * 64 + n] : ((k == 49) ? b0[n] : 0.0f);
        f0[j] = (_Float16)v0;
        f1[j] = (_Float16)W1[k * 64 + n];
      }
      B0f[t][s] = f0;
      B1f[t][s] = f1;
    }
  }
  float b1n[4], woutm[4];
#pragma unroll
  for (int t = 0; t < 4; ++t) {
    b1n[t]   = b1[t * 16 + m];
    woutm[t] = Wout[t * 16 + m];
  }
  const float boutBL = bout[0] + BASE_LOGIT;

  // one-time: constant feature cols. col 17 (k=49) = 1.0 bias slot; 18..31 = 0 K-pad.
  {
    half8 zc = (half8)(_Float16)0.0f;
    half8 c16 = zc; c16[1] = (_Float16)1.0f;  // col16 placeholder (s8, overwritten), col17=1
    *(half8*)&F[lane][16] = c16;
    *(half8*)&F[lane][24] = zc;
  }

  const f32x4 z = {0.0f, 0.0f, 0.0f, 0.0f};

  for (int g = blockIdx.x; g < ngroups; g += gridDim.x) {
    const int gbase = g * 64;

    // ---- P1: all-lane point loads + Fourier features (Chebyshev) ----
    const int   ti = tix[gbase + lane];
    const float rh = rho[gbase + lane];
    const float rev = 0.5f * rh;  // v_sin/v_cos take revolutions
    const float c1 = __builtin_amdgcn_cosf(rev);
    const float s1 = __builtin_amdgcn_sinf(rev);
    float cs[8], sn[8];
    cs[0] = c1; sn[0] = s1;
    {
      float cm2 = 1.0f, cm1 = c1, sm2 = 0.0f, sm1 = s1;
      const float tc = 2.0f * c1;
#pragma unroll
      for (int k = 1; k < 8; ++k) {
        const float ck = tc * cm1 - cm2;
        const float sk = tc * sm1 - sm2;
        cs[k] = ck; sn[k] = sk;
        cm2 = cm1; cm1 = ck; sm2 = sm1; sm1 = sk;
      }
    }
    // F row = this lane's point: [rho, c1..c8, s1..s8]
    half8 h0, h1;
    h0[0] = (_Float16)rh;
#pragma unroll
    for (int k = 0; k < 7; ++k) h0[1 + k] = (_Float16)cs[k];
    h1[0] = (_Float16)cs[7];
#pragma unroll
    for (int k = 0; k < 7; ++k) h1[1 + k] = (_Float16)sn[k];
    *(half8*)&F[lane][0] = h0;
    *(half8*)&F[lane][8] = h1;
    F[lane][16] = (_Float16)sn[7];

    __syncthreads();  // single-wave wg: cheap; features visible

#pragma unroll
    for (int st = 0; st < 4; ++st) {
      _Float16 (*Hb)[72] = H[st & 1];

      // ---- L0 (transposed): D = W0^T · X^T, rows=hidden, cols=points ----
      // B-op s0: emb gather — lane(m,q) holds emb[point st*16+m][q*8..+8]
      const int tim  = __shfl(ti, st * 16 + m, 64);
      const int idxm = min(max(tim - 1, 0), 510);
      const float* erow = emb + (size_t)idxm * 32 + q * 8;
      const f32x4 e0 = *(const f32x4*)erow;
      const f32x4 e1 = *(const f32x4*)(erow + 4);
      half8 X0;
#pragma unroll
      for (int j = 0; j < 4; ++j) {
        X0[j]     = (_Float16)e0[j];
        X0[4 + j] = (_Float16)e1[j];
      }
      // B-op s1: features of point st*16+m
      const half8 X1 = *(const half8*)&F[st * 16 + m][q * 8];

      f32x4 acc[4];
#pragma unroll
      for (int t = 0; t < 4; ++t) {
        f32x4 a = __builtin_amdgcn_mfma_f32_16x16x32_f16(B0f[t][0], X0, z, 0, 0, 0);
        a = __builtin_amdgcn_mfma_f32_16x16x32_f16(B0f[t][1], X1, a, 0, 0, 0);
        acc[t] = a;
      }
      // epilogue: lane(m,q) reg r = preact[hidden=t*16+q*4+r][point=st*16+m]
      // silu -> packed f16 -> contiguous 8B store per t
#pragma unroll
      for (int t = 0; t < 4; ++t) {
        half4v hh;
#pragma unroll
        for (int r = 0; r < 4; ++r) hh[r] = (_Float16)siluf(acc[t][r]);
        *(half4v*)&Hb[m][t * 16 + q * 4] = hh;
      }

      __syncthreads();  // h1 visible (also drains prior sub-tile's H reads: WAR-safe)

      // ---- L1 (untransposed): D = h1 · W1, rows=points, cols=hidden ----
      const half8 Y0 = *(const half8*)&Hb[m][q * 8];
      const half8 Y1 = *(const half8*)&Hb[m][32 + q * 8];
#pragma unroll
      for (int t = 0; t < 4; ++t) {
        f32x4 a = __builtin_amdgcn_mfma_f32_16x16x32_f16(Y0, B1f[t][0], z, 0, 0, 0);
        a = __builtin_amdgcn_mfma_f32_16x16x32_f16(Y1, B1f[t][1], a, 0, 0, 0);
        acc[t] = a;
      }
      // epilogue: C[point=q*4+r][hidden=t*16+m]; fuse bias+silu+Wout dot in regs
      float dot0 = 0.0f, dot1 = 0.0f, dot2 = 0.0f, dot3 = 0.0f;
#pragma unroll
      for (int t = 0; t < 4; ++t) {
        dot0 = fmaf(siluf(acc[t][0] + b1n[t]), woutm[t], dot0);
        dot1 = fmaf(siluf(acc[t][1] + b1n[t]), woutm[t], dot1);
        dot2 = fmaf(siluf(acc[t][2] + b1n[t]), woutm[t], dot2);
        dot3 = fmaf(siluf(acc[t][3] + b1n[t]), woutm[t], dot3);
      }
      // reduce over the 16 m-lanes within each q-group
#pragma unroll
      for (int mask = 1; mask <= 8; mask <<= 1) {
        dot0 += __shfl_xor(dot0, mask, 64);
        dot1 += __shfl_xor(dot1, mask, 64);
        dot2 += __shfl_xor(dot2, mask, 64);
        dot3 += __shfl_xor(dot3, mask, 64);
      }
      // lane(m<4, q) stores point st*16 + q*4 + m  (value dot[m])
      const float d = (m & 2) ? ((m & 1) ? dot3 : dot2) : ((m & 1) ? dot1 : dot0);
      const float theta = sigf(d + boutBL);
      const int   tis = __shfl(ti, st * 16 + q * 4 + (m & 3), 64);
      const float o = (tis == 0) ? IC_VAL : theta * CSANMAX;
      if (m < 4) out[gbase + st * 16 + q * 4 + m] = o;
    }
  }
}

extern "C" void kernel_launch(void* const* d_in, const int* in_sizes, int n_in,
                              void* d_out, int out_size, void* d_ws, size_t ws_size,
                              hipStream_t stream) {
  const int*   tix  = (const int*)d_in[0];
  const float* rho  = (const float*)d_in[1];
  const float* emb  = (const float*)d_in[2];
  const float* W0   = (const float*)d_in[3];
  const float* b0   = (const float*)d_in[4];
  const float* W1   = (const float*)d_in[5];
  const float* b1   = (const float*)d_in[6];
  const float* Wout = (const float*)d_in[7];
  const float* bout = (const float*)d_in[8];
  float* outp = (float*)d_out;

  const int n       = in_sizes[0];   // 2,000,000 (divisible by 64)
  const int ngroups = n / 64;        // 31,250 groups of 64 points

  int grid = 4096;                   // 1 wave/block; grid-stride over groups
  if (grid > ngroups) grid = ngroups;
  mlp_kernel<<<dim3(grid), dim3(64), 0, stream>>>(
      tix, rho, emb, W0, b0, W1, b1, Wout, bout, outp, ngroups);
}